// Round 6
// baseline (15781.494 us; speedup 1.0000x reference)
//
#include <hip/hip_runtime.h>

#define T_SEQ 512
#define BATCH 64
#define DIN0  512
#define D_H   1024
#define D_OUT 512

typedef __attribute__((ext_vector_type(8))) short short8;
typedef __attribute__((ext_vector_type(4))) float f32x4;

__device__ inline float bf2f(unsigned short u) {
    unsigned x = ((unsigned)u) << 16;
    return __builtin_bit_cast(float, x);
}
__device__ inline unsigned short f2bf(float f) {
    unsigned x = __builtin_bit_cast(unsigned, f);
    unsigned r = (x + 0x7fffu + ((x >> 16) & 1u)) >> 16;
    return (unsigned short)r;
}
__device__ inline float fast_sigmoid(float x) { return 1.f / (1.f + __expf(-x)); }
__device__ inline float fast_tanh(float x) {
    float ax = fabsf(x);
    float t = __expf(-2.f * ax);
    float r = (1.f - t) / (1.f + t);
    return copysignf(r, x);
}

// ---- coherence-point primitives (proven rounds 2/4/5) ----
__device__ inline void async_ld16_cohere(const void* g, void* l) {
    __builtin_amdgcn_global_load_lds((const __attribute__((address_space(1))) void*)g,
                                     (__attribute__((address_space(3))) void*)l,
                                     16, 0, 17);
}
__device__ inline void store_u16_sc01(void* p, unsigned v) {
    asm volatile("global_store_short %0, %1, off sc0 sc1" :: "v"(p), "v"(v) : "memory");
}
__device__ inline void store16_sc01(void* p, short8 v) {
    asm volatile("global_store_dwordx4 %0, %1, off sc0 sc1" :: "v"(p), "v"(v) : "memory");
}
__device__ inline void store_flag(int* p, int v) {
    asm volatile("global_store_dword %0, %1, off sc0 sc1" :: "v"(p), "v"(v) : "memory");
}
__device__ inline int load_flag(const int* p) {
    int r;
    asm volatile("global_load_dword %0, %1, off sc0 sc1\n\ts_waitcnt vmcnt(0)"
                 : "=&v"(r) : "v"(p) : "memory");
    return r;
}

#define MFMA16(a, b, c) __builtin_amdgcn_mfma_f32_16x16x32_bf16((a), (b), (c), 0, 0, 0)

// ---------------- cast fp32 -> bf16 ----------------
__global__ void cast_kernel(const float* __restrict__ in, unsigned short* __restrict__ out, int n4) {
    int i = blockIdx.x * blockDim.x + threadIdx.x;
    int stride = gridDim.x * blockDim.x;
    for (; i < n4; i += stride) {
        float4 v = ((const float4*)in)[i];
        ushort4 o;
        o.x = f2bf(v.x); o.y = f2bf(v.y); o.z = f2bf(v.z); o.w = f2bf(v.w);
        ((ushort4*)out)[i] = o;
    }
}

// ---------------- fused 2-layer GRU scan ----------------
// 64 blocks x 256 threads (4 waves). layer = bid>>5 (32 blocks each),
// rg = 2 row-groups of 32 batch rows, cb = 16 col-blocks of 64 h-cols.
// L0 step t: x-GEMM (overlaps poll) -> fetch h0(t) slab -> h-GEMM ->
//   publish h0(t+1)+y0(t) write-through -> flag t+2.
// L1 step t: poll F0>=t+2 & F1>=t+1 -> fetch y0(t)+h1(t) slabs ->
//   x-GEMM (A from y0 stage) + h-GEMM -> publish h1(t+1) (+y1 cached).
// LDS (ushorts): h-stage [32][1024] @0 (also reused as h_out [32][64] in
// epilogue); y0-stage [32][1024] @32768 (layer 1 only). 128KB.
__global__ __launch_bounds__(256, 1) void gru_fused(
    const unsigned short* __restrict__ x_bf,   // [T][B][512]
    const unsigned short* __restrict__ wih0, const unsigned short* __restrict__ whh0,
    const float* __restrict__ bih0, const float* __restrict__ bhh0,
    const unsigned short* __restrict__ wih1, const unsigned short* __restrict__ whh1,
    const float* __restrict__ bih1, const float* __restrict__ bhh1,
    const float* __restrict__ h0_all,          // [2][B][1024] fp32
    unsigned short* __restrict__ hbuf0, unsigned short* __restrict__ hbuf1,
    unsigned short* __restrict__ y0,           // [T][B][1024] (sc01 exchange)
    unsigned short* __restrict__ y1,           // [T][B][1024]
    int* __restrict__ flags)                   // [4 groups][64 ints]
{
    extern __shared__ unsigned short lds[];

    const int tid  = threadIdx.x;
    const int lane = tid & 63;
    const int wv   = tid >> 6;
    const int bid  = blockIdx.x;
    const int layer = bid >> 5, lbid = bid & 31;
    const int rg = lbid >> 4, cb = lbid & 15;
    const int r0 = rg * 32, c0 = cb * 64, cw = c0 + wv * 16;

    int* const F0    = flags + rg * 64;          // layer-0 group for this rg
    int* const F1    = flags + (2 + rg) * 64;    // layer-1 group
    int* const Fmine = (layer == 0 ? F0 : F1) + cb;

    const unsigned short* wih = layer ? wih1 : wih0;
    const unsigned short* whh = layer ? whh1 : whh0;
    const float* bih = layer ? bih1 : bih0;
    const float* bhh = layer ? bhh1 : bhh0;
    const float* h0  = h0_all + (size_t)layer * BATCH * D_H;
    unsigned short* const hbw = layer ? hbuf1 : hbuf0;

    const int arow = lane & 15;          // MFMA A-row / B-col within fragment
    const int ako  = (lane >> 4) * 8;    // k sub-offset
    const int swz  = (arow & 7) << 3;
    const int gc   = cw + arow;          // this lane's h column
    const int crow = (lane >> 4) * 4;    // C-fragment row base

    const float b_r  = bih[gc] + bhh[gc];
    const float b_z  = bih[D_H + gc] + bhh[D_H + gc];
    const float b_xn = bih[2 * D_H + gc];
    const float b_hn = bhh[2 * D_H + gc];

    // ---- init h state (2 row-fragments x 4 rows), publish, flag=1 ----
    float hprev[2][4];
    #pragma unroll
    for (int rf = 0; rf < 2; ++rf)
        #pragma unroll
        for (int i = 0; i < 4; ++i) {
            int rr = r0 + rf * 16 + crow + i;
            float v = h0[(size_t)rr * D_H + gc];
            hprev[rf][i] = v;
            store_u16_sc01(&hbw[(size_t)rr * D_H + gc], (unsigned)f2bf(v));
        }
    asm volatile("s_waitcnt vmcnt(0)" ::: "memory");
    __syncthreads();
    if (tid == 0) store_flag(Fmine, 1);

    for (int t = 0; t < T_SEQ; ++t) {
        const unsigned short* hb  = hbw + (t & 1) * (BATCH * D_H);
        unsigned short*       hbn = hbw + ((t & 1) ^ 1) * (BATCH * D_H);

        f32x4 fr[2]  = {{0.f,0.f,0.f,0.f},{0.f,0.f,0.f,0.f}};
        f32x4 fz[2]  = {{0.f,0.f,0.f,0.f},{0.f,0.f,0.f,0.f}};
        f32x4 fnx[2] = {{0.f,0.f,0.f,0.f},{0.f,0.f,0.f,0.f}};
        f32x4 fnh[2] = {{0.f,0.f,0.f,0.f},{0.f,0.f,0.f,0.f}};

        if (layer == 0) {
            // ---- x-phase (input always ready; overlaps peers finishing) ----
            const unsigned short* xt = x_bf + (size_t)t * BATCH * DIN0;
            #pragma unroll 4
            for (int k = 0; k < DIN0; k += 32) {
                short8 bn = *(const short8*)&wih[(size_t)(2*D_H + cw + arow) * DIN0 + k + ako];
                short8 br = *(const short8*)&wih[(size_t)(        cw + arow) * DIN0 + k + ako];
                short8 bz = *(const short8*)&wih[(size_t)(D_H   + cw + arow) * DIN0 + k + ako];
                short8 a0 = *(const short8*)&xt[(size_t)(r0      + arow) * DIN0 + k + ako];
                short8 a1 = *(const short8*)&xt[(size_t)(r0 + 16 + arow) * DIN0 + k + ako];
                fr[0]  = MFMA16(a0, br, fr[0]);  fr[1]  = MFMA16(a1, br, fr[1]);
                fz[0]  = MFMA16(a0, bz, fz[0]);  fz[1]  = MFMA16(a1, bz, fz[1]);
                fnx[0] = MFMA16(a0, bn, fnx[0]); fnx[1] = MFMA16(a1, bn, fnx[1]);
            }
            // ---- poll peers: h0(t) published? ----
            if (wv == 0) {
                const int* fp = F0 + (lane & 15);
                for (int it = 0; it < 100000; ++it) {
                    int f = load_flag(fp);
                    if (__all(f >= t + 1)) break;
                    __builtin_amdgcn_s_sleep(1);
                }
            }
            __syncthreads();
            // ---- fetch h slab [32][1024] (64 gll, 16/wave) ----
            #pragma unroll
            for (int j = 0; j < 16; ++j) {
                int i = wv * 16 + j, row = i >> 1, hf = i & 1, sw8 = row & 7;
                const unsigned short* src =
                    hb + (size_t)(r0 + row) * D_H + (hf * 64 + (lane ^ sw8)) * 8;
                async_ld16_cohere(src, &lds[row * 1024 + hf * 512]);
            }
            asm volatile("s_waitcnt vmcnt(0)" ::: "memory");
            __syncthreads();
            __builtin_amdgcn_sched_barrier(0);
        } else {
            // ---- poll: y0(t) (F0>=t+2) and h1(t) (F1>=t+1) ----
            if (wv == 0) {
                const int* fp0 = F0 + (lane & 15);
                const int* fp1 = F1 + (lane & 15);
                for (int it = 0; it < 100000; ++it) {
                    int f1 = load_flag(fp1);
                    int f0 = load_flag(fp0);
                    if (__all((f1 >= t + 1) && (f0 >= t + 2))) break;
                    __builtin_amdgcn_s_sleep(1);
                }
            }
            __syncthreads();
            // ---- fetch h1 slab + y0 slab (128 gll, 32/wave) ----
            const unsigned short* y0t = y0 + (size_t)t * BATCH * D_H;
            #pragma unroll
            for (int j = 0; j < 16; ++j) {
                int i = wv * 16 + j, row = i >> 1, hf = i & 1, sw8 = row & 7;
                size_t roff = (size_t)(r0 + row) * D_H + (hf * 64 + (lane ^ sw8)) * 8;
                async_ld16_cohere(hb  + roff, &lds[row * 1024 + hf * 512]);
                async_ld16_cohere(y0t + roff, &lds[32768 + row * 1024 + hf * 512]);
            }
            asm volatile("s_waitcnt vmcnt(0)" ::: "memory");
            __syncthreads();
            __builtin_amdgcn_sched_barrier(0);
            // ---- x-phase: A from y0 stage ----
            #pragma unroll 4
            for (int k = 0; k < D_H; k += 32) {
                short8 bn = *(const short8*)&wih[(size_t)(2*D_H + cw + arow) * D_H + k + ako];
                short8 br = *(const short8*)&wih[(size_t)(        cw + arow) * D_H + k + ako];
                short8 bz = *(const short8*)&wih[(size_t)(D_H   + cw + arow) * D_H + k + ako];
                short8 a0 = *(const short8*)&lds[32768 + (((     arow) * 1024 + k + ako) ^ swz)];
                short8 a1 = *(const short8*)&lds[32768 + (((16 + arow) * 1024 + k + ako) ^ swz)];
                fr[0]  = MFMA16(a0, br, fr[0]);  fr[1]  = MFMA16(a1, br, fr[1]);
                fz[0]  = MFMA16(a0, bz, fz[0]);  fz[1]  = MFMA16(a1, bz, fz[1]);
                fnx[0] = MFMA16(a0, bn, fnx[0]); fnx[1] = MFMA16(a1, bn, fnx[1]);
            }
        }

        // ---- h-phase (both layers): A from h stage, B streamed from L2 ----
        #pragma unroll 4
        for (int k = 0; k < D_H; k += 32) {
            short8 bn = *(const short8*)&whh[(size_t)(2*D_H + cw + arow) * D_H + k + ako];
            short8 br = *(const short8*)&whh[(size_t)(        cw + arow) * D_H + k + ako];
            short8 bz = *(const short8*)&whh[(size_t)(D_H   + cw + arow) * D_H + k + ako];
            short8 a0 = *(const short8*)&lds[(((     arow) * 1024 + k + ako) ^ swz)];
            short8 a1 = *(const short8*)&lds[(((16 + arow) * 1024 + k + ako) ^ swz)];
            fr[0]  = MFMA16(a0, br, fr[0]);  fr[1]  = MFMA16(a1, br, fr[1]);
            fz[0]  = MFMA16(a0, bz, fz[0]);  fz[1]  = MFMA16(a1, bz, fz[1]);
            fnh[0] = MFMA16(a0, bn, fnh[0]); fnh[1] = MFMA16(a1, bn, fnh[1]);
        }
        __syncthreads();   // (A) all waves done reading stages

        // ---- epilogue: gates + state; h16 tile into LDS h_out [32][64] ----
        #pragma unroll
        for (int rf = 0; rf < 2; ++rf)
            #pragma unroll
            for (int i = 0; i < 4; ++i) {
                float r = fast_sigmoid(fr[rf][i] + b_r);
                float z = fast_sigmoid(fz[rf][i] + b_z);
                float n = fast_tanh(fnx[rf][i] + b_xn + r * (fnh[rf][i] + b_hn));
                float hn = (1.f - z) * n + z * hprev[rf][i];
                hprev[rf][i] = hn;
                lds[(rf * 16 + crow + i) * 64 + wv * 16 + arow] = f2bf(hn);
            }
        __syncthreads();   // (B) h_out complete

        // ---- coalesced publish: 256 threads x 16B ----
        {
            int srow = tid >> 3, sc8 = (tid & 7) * 8;
            short8 val = *(const short8*)&lds[srow * 64 + sc8];
            size_t goff = (size_t)(r0 + srow) * D_H + c0 + sc8;
            store16_sc01(&hbn[goff], val);
            if (layer == 0)
                store16_sc01(&y0[(size_t)t * BATCH * D_H + goff], val);
            else
                *(short8*)&y1[(size_t)t * BATCH * D_H + goff] = val;  // cached; next kernel
        }
        asm volatile("s_waitcnt vmcnt(0)" ::: "memory");
        __syncthreads();   // (C) all drained
        if (tid == 0) store_flag(Fmine, t + 2);
    }
}

// ---------------- fused LayerNorm + output projection ----------------
__global__ __launch_bounds__(256) void ln_proj(
    const unsigned short* __restrict__ y1,   // [TB][1024] bf16
    const float* __restrict__ gamma, const float* __restrict__ beta,
    const unsigned short* __restrict__ ffw,  // [512][1024] bf16
    const float* __restrict__ ffb,           // [512]
    float* __restrict__ out)                 // [TB][512]
{
    __shared__ unsigned short ylds[16 * 1024];
    const int row0 = blockIdx.x * 16;
    const int tid = threadIdx.x;

    {
        const int rr = tid >> 4, l16 = tid & 15;
        const unsigned short* yrow = y1 + (size_t)(row0 + rr) * D_H;
        float s = 0.f, sq = 0.f;
        #pragma unroll
        for (int j8 = 0; j8 < 8; ++j8) {
            int k = l16 * 64 + j8 * 8;
            short8 v = *(const short8*)&yrow[k];
            int idx = (rr * 1024 + k) ^ ((rr & 7) << 3);
            *(short8*)&ylds[idx] = v;
            #pragma unroll
            for (int j = 0; j < 8; ++j) {
                float f = bf2f((unsigned short)v[j]);
                s += f; sq += f * f;
            }
        }
        #pragma unroll
        for (int o = 1; o < 16; o <<= 1) {
            s  += __shfl_xor(s, o, 64);
            sq += __shfl_xor(sq, o, 64);
        }
        float mu = s * (1.f / 1024.f);
        float var = sq * (1.f / 1024.f) - mu * mu;
        float rstd = rsqrtf(var + 1e-5f);
        #pragma unroll
        for (int j8 = 0; j8 < 8; ++j8) {
            int k = l16 * 64 + j8 * 8;
            int idx = (rr * 1024 + k) ^ ((rr & 7) << 3);
            short8 v = *(short8*)&ylds[idx];
            short8 o8;
            #pragma unroll
            for (int j = 0; j < 8; ++j) {
                float f = bf2f((unsigned short)v[j]);
                f = (f - mu) * rstd * gamma[k + j] + beta[k + j];
                o8[j] = (short)f2bf(f);
            }
            *(short8*)&ylds[idx] = o8;
        }
    }
    __syncthreads();

    const int w = tid >> 6, lane = tid & 63;
    const int cbase = w * 128;
    const int arow = lane & 15, ako = (lane >> 4) * 8;
    f32x4 acc[8] = {};
    for (int k = 0; k < D_H; k += 32) {
        int aidx = (arow * 1024 + k + ako) ^ ((arow & 7) << 3);
        short8 a = *(const short8*)&ylds[aidx];
        #pragma unroll
        for (int n = 0; n < 8; ++n) {
            int col = cbase + n * 16 + (lane & 15);
            short8 b = *(const short8*)&ffw[col * 1024 + k + ako];
            acc[n] = __builtin_amdgcn_mfma_f32_16x16x32_bf16(a, b, acc[n], 0, 0, 0);
        }
    }
    #pragma unroll
    for (int n = 0; n < 8; ++n) {
        int col = cbase + n * 16 + (lane & 15);
        float bb = ffb[col];
        #pragma unroll
        for (int i = 0; i < 4; ++i) {
            int rr = row0 + (lane >> 4) * 4 + i;
            out[(size_t)rr * D_OUT + col] = acc[n][i] + bb;
        }
    }
}

// ---------------- launch ----------------
extern "C" void kernel_launch(void* const* d_in, const int* in_sizes, int n_in,
                              void* d_out, int out_size, void* d_ws, size_t ws_size,
                              hipStream_t stream) {
    const float* x     = (const float*)d_in[0];
    const float* h     = (const float*)d_in[1];
    const float* w_ih0 = (const float*)d_in[2];
    const float* w_hh0 = (const float*)d_in[3];
    const float* b_ih0 = (const float*)d_in[4];
    const float* b_hh0 = (const float*)d_in[5];
    const float* w_ih1 = (const float*)d_in[6];
    const float* w_hh1 = (const float*)d_in[7];
    const float* b_ih1 = (const float*)d_in[8];
    const float* b_hh1 = (const float*)d_in[9];
    const float* ln_g  = (const float*)d_in[10];
    const float* ln_b  = (const float*)d_in[11];
    const float* ff_w  = (const float*)d_in[12];
    const float* ff_b  = (const float*)d_in[13];
    float* out = (float*)d_out;

    char* ws = (char*)d_ws;
    size_t off = 0;
    auto alloc = [&](size_t bytes) {
        void* p = ws + off;
        off = (off + bytes + 255) & ~(size_t)255;
        return p;
    };
    unsigned short* x_bf   = (unsigned short*)alloc((size_t)T_SEQ * BATCH * DIN0 * 2);
    unsigned short* y1_bf  = (unsigned short*)alloc((size_t)T_SEQ * BATCH * D_H * 2);
    unsigned short* wih0_b = (unsigned short*)alloc((size_t)3 * D_H * DIN0 * 2);
    unsigned short* whh0_b = (unsigned short*)alloc((size_t)3 * D_H * D_H * 2);
    unsigned short* wih1_b = (unsigned short*)alloc((size_t)3 * D_H * D_H * 2);
    unsigned short* whh1_b = (unsigned short*)alloc((size_t)3 * D_H * D_H * 2);
    unsigned short* ffw_b  = (unsigned short*)alloc((size_t)D_OUT * D_H * 2);
    unsigned short* hbuf0  = (unsigned short*)alloc((size_t)2 * BATCH * D_H * 2);
    unsigned short* hbuf1  = (unsigned short*)alloc((size_t)2 * BATCH * D_H * 2);
    int*            flags  = (int*)alloc(4 * 64 * 4);
    if (off > ws_size) return;

    unsigned short* y0_bf = (unsigned short*)d_out;  // 64MB staging, overwritten by ln_proj

    hipMemsetAsync(flags, 0, 4 * 64 * 4, stream);

    auto castl = [&](const float* src, unsigned short* dst, int n) {
        int n4 = n / 4;
        int blocks = (n4 + 255) / 256;
        if (blocks > 2048) blocks = 2048;
        hipLaunchKernelGGL(cast_kernel, dim3(blocks), dim3(256), 0, stream, src, dst, n4);
    };
    castl(x,     x_bf,   T_SEQ * BATCH * DIN0);
    castl(w_ih0, wih0_b, 3 * D_H * DIN0);
    castl(w_hh0, whh0_b, 3 * D_H * D_H);
    castl(w_ih1, wih1_b, 3 * D_H * D_H);
    castl(w_hh1, whh1_b, 3 * D_H * D_H);
    castl(ff_w,  ffw_b,  D_OUT * D_H);

    const int ldsb = 131072;   // h-stage 64KB + y0-stage 64KB
    hipFuncSetAttribute((const void*)&gru_fused,
                        hipFuncAttributeMaxDynamicSharedMemorySize, ldsb);

    hipLaunchKernelGGL(gru_fused, dim3(64), dim3(256), ldsb, stream,
        x_bf, wih0_b, whh0_b, b_ih0, b_hh0,
        wih1_b, whh1_b, b_ih1, b_hh1,
        h, hbuf0, hbuf1, y0_bf, y1_bf, flags);

    hipLaunchKernelGGL(ln_proj, dim3(T_SEQ * BATCH / 16), dim3(256), 0, stream,
        y1_bf, ln_g, ln_b, ffw_b, ff_b, out);
}

// Round 9
// 8035.815 us; speedup vs baseline: 1.9639x; 1.9639x over previous
//
#include <hip/hip_runtime.h>

#define T_SEQ 512
#define BATCH 64
#define DIN0  512
#define D_H   1024
#define D_OUT 512
#define NBLK  256
#define BH    (BATCH * D_H)   // also tile-buffer size: 4rg*64cb*256 = 65536

typedef __attribute__((ext_vector_type(8))) short short8;
typedef __attribute__((ext_vector_type(4))) float f32x4;

__device__ inline float bf2f(unsigned short u) {
    unsigned x = ((unsigned)u) << 16;
    return __builtin_bit_cast(float, x);
}
__device__ inline unsigned short f2bf(float f) {
    unsigned x = __builtin_bit_cast(unsigned, f);
    unsigned r = (x + 0x7fffu + ((x >> 16) & 1u)) >> 16;
    return (unsigned short)r;
}
__device__ inline float fast_sigmoid(float x) { return 1.f / (1.f + __expf(-x)); }
__device__ inline float fast_tanh(float x) {
    float ax = fabsf(x);
    float t = __expf(-2.f * ax);
    float r = (1.f - t) / (1.f + t);
    return copysignf(r, x);
}

// ---- coherence-point primitives (proven rounds 2/4/5/6) ----
__device__ inline void async_ld16_cohere(const void* g, void* l) {
    __builtin_amdgcn_global_load_lds((const __attribute__((address_space(1))) void*)g,
                                     (__attribute__((address_space(3))) void*)l,
                                     16, 0, 17);
}
__device__ inline void store_u16_sc01(void* p, unsigned v) {
    asm volatile("global_store_short %0, %1, off sc0 sc1" :: "v"(p), "v"(v) : "memory");
}
__device__ inline void store16_sc01(void* p, short8 v) {
    asm volatile("global_store_dwordx4 %0, %1, off sc0 sc1" :: "v"(p), "v"(v) : "memory");
}
__device__ inline short8 load16_sc01_wait(const void* p) {
    short8 r;
    asm volatile("global_load_dwordx4 %0, %1, off sc0 sc1\n\ts_waitcnt vmcnt(0)"
                 : "=&v"(r) : "v"(p) : "memory");
    return r;
}

// ---------------- cast fp32 -> bf16 ----------------
__global__ void cast_kernel(const float* __restrict__ in, unsigned short* __restrict__ out, int n4) {
    int i = blockIdx.x * blockDim.x + threadIdx.x;
    int stride = gridDim.x * blockDim.x;
    for (; i < n4; i += stride) {
        float4 v = ((const float4*)in)[i];
        ushort4 o;
        o.x = f2bf(v.x); o.y = f2bf(v.y); o.z = f2bf(v.z); o.w = f2bf(v.w);
        ((ushort4*)out)[i] = o;
    }
}

// ---------------- GRU layer scan (producer/consumer waves) ----------------
// 256 blocks x 128 threads (2 waves, 1 block/CU, 160KB LDS). Identical to the
// round-5 kernel EXCEPT the h exchange buffer is tile-blocked:
//   hbuf = [2][4rg * 64cb][16 rows][16 cols] bf16
// Publish: 16x16 tile assembled in stage LDS -> 32 lanes x 16B contiguous
// (2 x 256B fabric transactions). Fetch: linear 32KB copy (32 x 1KB issues).
// LDS (ushort elems): stage[16*1024] @0 ; WHn @16384 ; WHr @32768 ;
//   FULLZH: WHz @49152, WX @65536   else: WX @49152 (z streamed from L2).
template <int DIN, bool FULLZH>
__global__ __launch_bounds__(128, 1) void gru_scan(
    const unsigned short* __restrict__ xseq,  // [T][B][DIN] bf16 (row-major)
    const unsigned short* __restrict__ wih,   // [3H][DIN] bf16 (r,z,n)
    const unsigned short* __restrict__ whh,   // [3H][H]  bf16
    const float* __restrict__ bih, const float* __restrict__ bhh,
    const float* __restrict__ h0,             // [B][H] fp32
    unsigned short* __restrict__ hbuf,        // [2][BH] bf16 TILE-BLOCKED exchange
    unsigned short* __restrict__ Y,           // [T][B][H] bf16 (row-major)
    unsigned short* __restrict__ flags)       // [4 rg][64] ushort
{
    extern __shared__ unsigned short lds[];
    constexpr int WX_BASE = FULLZH ? 65536 : 49152;

    const int tid  = threadIdx.x;
    const int lane = tid & 63;
    const int wv   = tid >> 6;
    const int bid  = blockIdx.x;
    const int xcd  = bid & 7;
    const int rg   = xcd >> 1;                      // 0..3 (rg pinned to 2 XCDs)
    const int cb   = ((bid >> 3) << 1) | (xcd & 1); // 0..63
    const int c0   = cb * 16, r0 = rg * 16;
    const int tile = rg * 64 + cb;                  // this block's tile index

    unsigned short* const frg = flags + rg * 64;

    // ---- stage weights into LDS (both waves, 128 threads) ----
    {
        const int NG = FULLZH ? 3 : 2;
        for (int g = 0; g < NG; ++g) {
            const int grow = (g == 0) ? 2 * D_H : (g == 1 ? 0 : D_H);  // n, r, z
            unsigned short* W = lds + 16384 + g * 16384;
            for (int i = tid; i < 16 * 128; i += 128) {
                int c = i >> 7, kb = i & 127;
                int el = (c * 1024 + kb * 8) ^ ((c & 7) << 3);
                *(short8*)&W[el] = *(const short8*)&whh[(size_t)(grow + c0 + c) * D_H + kb * 8];
            }
        }
        for (int g = 0; g < 2; ++g) {
            const int grow = (g == 0) ? 2 * D_H : 0;   // n, r
            unsigned short* W = lds + WX_BASE + g * 16 * DIN;
            for (int i = tid; i < 16 * (DIN / 8); i += 128) {
                int c = i / (DIN / 8), kb = i % (DIN / 8);
                int el = (c * DIN + kb * 8) ^ ((c & 7) << 3);
                *(short8*)&W[el] = *(const short8*)&wih[(size_t)(grow + c0 + c) * DIN + kb * 8];
            }
        }
    }
    __syncthreads();

    // ---- wave0: init h tile (fp32 state in regs), publish tile, flag=1 ----
    const int gc   = c0 + (lane & 15);
    const int crow = (lane >> 4) * 4;
    const int arow = lane & 15;
    const int ako  = (lane >> 4) * 8;
    const int swz  = (arow & 7) << 3;
    float hprev[4];
    float b_r, b_z, b_xn, b_hn;
    if (wv == 0) {
        #pragma unroll
        for (int i = 0; i < 4; ++i) {
            float v = h0[(size_t)(r0 + crow + i) * D_H + gc];
            hprev[i] = v;
            // tile-blocked: [tile][row][col]
            store_u16_sc01(&hbuf[tile * 256 + (crow + i) * 16 + arow], (unsigned)f2bf(v));
        }
        asm volatile("s_waitcnt vmcnt(0)" ::: "memory");
        if (lane == 0) store_u16_sc01(&frg[cb], 1u);
        b_r  = bih[gc] + bhh[gc];
        b_z  = bih[D_H + gc] + bhh[D_H + gc];
        b_xn = bih[2 * D_H + gc];
        b_hn = bhh[2 * D_H + gc];
    }

    f32x4 fr, fz, fnx, fnh;

    for (int t = 0; t < T_SEQ; ++t) {
        const unsigned short* hbt  = hbuf + (t & 1) * BH + rg * 64 * 256;  // rg's 64 tiles
        unsigned short*       hbnt = hbuf + ((t & 1) ^ 1) * BH + tile * 256;
        const unsigned short* xt   = xseq + (size_t)t * BATCH * DIN;
        unsigned short*       Yt   = Y + (size_t)t * BATCH * D_H;

        if (wv == 1) {
            // ---- sync wave: poll packed flags, then linear 32KB tile fetch ----
            const int p = t + 1;
            const unsigned short* fp = frg + (lane & 7) * 8;
            for (int it = 0; it < 200000; ++it) {
                short8 f = load16_sc01_wait(fp);
                bool ok = true;
                #pragma unroll
                for (int j = 0; j < 8; ++j)
                    ok &= ((unsigned short)f[j] >= (unsigned)p);
                if (__all(ok)) break;
                __builtin_amdgcn_s_sleep(1);
            }
            #pragma unroll
            for (int i = 0; i < 32; ++i)   // 32 x (64 lanes x 16B) = 32KB linear
                async_ld16_cohere(hbt + i * 512 + lane * 8, &lds[i * 512]);
            asm volatile("s_waitcnt vmcnt(0)" ::: "memory");
        } else {
            // ---- compute wave: x-phase (independent of h(t)) ----
            fr = (f32x4){0.f, 0.f, 0.f, 0.f}; fz = fr; fnx = fr; fnh = fr;
            #pragma unroll 4
            for (int k = 0; k < DIN; k += 32) {
                short8 a  = *(const short8*)&xt[(size_t)(r0 + arow) * DIN + k + ako];
                int el    = (arow * DIN + k + ako) ^ swz;
                short8 bn = *(const short8*)&lds[WX_BASE + el];
                short8 br = *(const short8*)&lds[WX_BASE + 16 * DIN + el];
                short8 bz = *(const short8*)&wih[(size_t)(D_H + c0 + arow) * DIN + k + ako];
                fr  = __builtin_amdgcn_mfma_f32_16x16x32_bf16(a, br, fr, 0, 0, 0);
                fz  = __builtin_amdgcn_mfma_f32_16x16x32_bf16(a, bz, fz, 0, 0, 0);
                fnx = __builtin_amdgcn_mfma_f32_16x16x32_bf16(a, bn, fnx, 0, 0, 0);
            }
        }
        __syncthreads();   // stage holds h(t) tiles; wave0 done with x-phase

        if (wv == 0) {
            // ---- h-phase: A from stage tiles, B(n,r) from LDS, z per FULLZH ----
            #pragma unroll 4
            for (int k = 0; k < D_H; k += 32) {
                int sel   = ((k + ako) >> 4) * 256 + arow * 16 + ((k + ako) & 15);
                short8 a  = *(const short8*)&lds[sel];
                int el    = (arow * 1024 + k + ako) ^ swz;
                short8 bn = *(const short8*)&lds[16384 + el];
                short8 br = *(const short8*)&lds[32768 + el];
                short8 bz;
                if (FULLZH) bz = *(const short8*)&lds[49152 + el];
                else        bz = *(const short8*)&whh[(size_t)(D_H + c0 + arow) * D_H + k + ako];
                fr  = __builtin_amdgcn_mfma_f32_16x16x32_bf16(a, br, fr, 0, 0, 0);
                fz  = __builtin_amdgcn_mfma_f32_16x16x32_bf16(a, bz, fz, 0, 0, 0);
                fnh = __builtin_amdgcn_mfma_f32_16x16x32_bf16(a, bn, fnh, 0, 0, 0);
            }

            // ---- epilogue: gates + state; assemble out-tile in stage[0..255] ----
            unsigned short h16[4];
            #pragma unroll
            for (int i = 0; i < 4; ++i) {
                float r = fast_sigmoid(fr[i] + b_r);
                float z = fast_sigmoid(fz[i] + b_z);
                float n = fast_tanh(fnx[i] + b_xn + r * (fnh[i] + b_hn));
                float hn = (1.f - z) * n + z * hprev[i];
                hprev[i] = hn;
                h16[i] = f2bf(hn);
                lds[(crow + i) * 16 + arow] = h16[i];   // stage is dead now; reuse
            }
            // ---- coalesced publish: 32 lanes x 16B = 512B contiguous ----
            if (lane < 32) {
                short8 val = *(const short8*)&lds[lane * 8];
                store16_sc01(&hbnt[lane * 8], val);
            }
            asm volatile("s_waitcnt vmcnt(0)" ::: "memory");
            if (lane == 0) store_u16_sc01(&frg[cb], (unsigned)(t + 2));
            // Y stays row-major (consumed as GEMM input next layer): cached 2B
            #pragma unroll
            for (int i = 0; i < 4; ++i)
                Yt[(size_t)(r0 + crow + i) * D_H + gc] = h16[i];
        }
        __syncthreads();   // wave0 done with stage; wave1 may overwrite next iter
    }
}

// ---------------- fused LayerNorm + output projection ----------------
__global__ __launch_bounds__(256) void ln_proj(
    const unsigned short* __restrict__ y1,   // [TB][1024] bf16
    const float* __restrict__ gamma, const float* __restrict__ beta,
    const unsigned short* __restrict__ ffw,  // [512][1024] bf16
    const float* __restrict__ ffb,           // [512]
    float* __restrict__ out)                 // [TB][512]
{
    __shared__ unsigned short ylds[16 * 1024];
    const int row0 = blockIdx.x * 16;
    const int tid = threadIdx.x;

    {
        const int rr = tid >> 4, l16 = tid & 15;
        const unsigned short* yrow = y1 + (size_t)(row0 + rr) * D_H;
        float s = 0.f, sq = 0.f;
        #pragma unroll
        for (int j8 = 0; j8 < 8; ++j8) {
            int k = l16 * 64 + j8 * 8;
            short8 v = *(const short8*)&yrow[k];
            int idx = (rr * 1024 + k) ^ ((rr & 7) << 3);
            *(short8*)&ylds[idx] = v;
            #pragma unroll
            for (int j = 0; j < 8; ++j) {
                float f = bf2f((unsigned short)v[j]);
                s += f; sq += f * f;
            }
        }
        #pragma unroll
        for (int o = 1; o < 16; o <<= 1) {
            s  += __shfl_xor(s, o, 64);
            sq += __shfl_xor(sq, o, 64);
        }
        float mu = s * (1.f / 1024.f);
        float var = sq * (1.f / 1024.f) - mu * mu;
        float rstd = rsqrtf(var + 1e-5f);
        #pragma unroll
        for (int j8 = 0; j8 < 8; ++j8) {
            int k = l16 * 64 + j8 * 8;
            int idx = (rr * 1024 + k) ^ ((rr & 7) << 3);
            short8 v = *(short8*)&ylds[idx];
            short8 o8;
            #pragma unroll
            for (int j = 0; j < 8; ++j) {
                float f = bf2f((unsigned short)v[j]);
                f = (f - mu) * rstd * gamma[k + j] + beta[k + j];
                o8[j] = (short)f2bf(f);
            }
            *(short8*)&ylds[idx] = o8;
        }
    }
    __syncthreads();

    const int w = tid >> 6, lane = tid & 63;
    const int cbase = w * 128;
    const int arow = lane & 15, ako = (lane >> 4) * 8;
    f32x4 acc[8] = {};
    for (int k = 0; k < D_H; k += 32) {
        int aidx = (arow * 1024 + k + ako) ^ ((arow & 7) << 3);
        short8 a = *(const short8*)&ylds[aidx];
        #pragma unroll
        for (int n = 0; n < 8; ++n) {
            int col = cbase + n * 16 + (lane & 15);
            short8 b = *(const short8*)&ffw[col * 1024 + k + ako];
            acc[n] = __builtin_amdgcn_mfma_f32_16x16x32_bf16(a, b, acc[n], 0, 0, 0);
        }
    }
    #pragma unroll
    for (int n = 0; n < 8; ++n) {
        int col = cbase + n * 16 + (lane & 15);
        float bb = ffb[col];
        #pragma unroll
        for (int i = 0; i < 4; ++i) {
            int rr = row0 + (lane >> 4) * 4 + i;
            out[(size_t)rr * D_OUT + col] = acc[n][i] + bb;
        }
    }
}

// ---------------- launch ----------------
extern "C" void kernel_launch(void* const* d_in, const int* in_sizes, int n_in,
                              void* d_out, int out_size, void* d_ws, size_t ws_size,
                              hipStream_t stream) {
    const float* x     = (const float*)d_in[0];
    const float* h     = (const float*)d_in[1];
    const float* w_ih0 = (const float*)d_in[2];
    const float* w_hh0 = (const float*)d_in[3];
    const float* b_ih0 = (const float*)d_in[4];
    const float* b_hh0 = (const float*)d_in[5];
    const float* w_ih1 = (const float*)d_in[6];
    const float* w_hh1 = (const float*)d_in[7];
    const float* b_ih1 = (const float*)d_in[8];
    const float* b_hh1 = (const float*)d_in[9];
    const float* ln_g  = (const float*)d_in[10];
    const float* ln_b  = (const float*)d_in[11];
    const float* ff_w  = (const float*)d_in[12];
    const float* ff_b  = (const float*)d_in[13];
    float* out = (float*)d_out;

    char* ws = (char*)d_ws;
    size_t off = 0;
    auto alloc = [&](size_t bytes) {
        void* p = ws + off;
        off = (off + bytes + 255) & ~(size_t)255;
        return p;
    };
    unsigned short* x_bf   = (unsigned short*)alloc((size_t)T_SEQ * BATCH * DIN0 * 2);
    unsigned short* y1_bf  = (unsigned short*)alloc((size_t)T_SEQ * BATCH * D_H * 2);
    unsigned short* wih0_b = (unsigned short*)alloc((size_t)3 * D_H * DIN0 * 2);
    unsigned short* whh0_b = (unsigned short*)alloc((size_t)3 * D_H * D_H * 2);
    unsigned short* wih1_b = (unsigned short*)alloc((size_t)3 * D_H * D_H * 2);
    unsigned short* whh1_b = (unsigned short*)alloc((size_t)3 * D_H * D_H * 2);
    unsigned short* ffw_b  = (unsigned short*)alloc((size_t)D_OUT * D_H * 2);
    unsigned short* hbuf   = (unsigned short*)alloc((size_t)2 * BH * 2);
    unsigned short* flags  = (unsigned short*)alloc(2 * 4 * 64 * 2);   // 2 layers x 4rg x 64
    if (off > ws_size) return;

    unsigned short* y0_bf = (unsigned short*)d_out;  // 64MB staging, overwritten by ln_proj

    hipMemsetAsync(flags, 0, 2 * 4 * 64 * 2, stream);

    auto castl = [&](const float* src, unsigned short* dst, int n) {
        int n4 = n / 4;
        int blocks = (n4 + 255) / 256;
        if (blocks > 2048) blocks = 2048;
        hipLaunchKernelGGL(cast_kernel, dim3(blocks), dim3(256), 0, stream, src, dst, n4);
    };
    castl(x,     x_bf,   T_SEQ * BATCH * DIN0);
    castl(w_ih0, wih0_b, 3 * D_H * DIN0);
    castl(w_hh0, whh0_b, 3 * D_H * D_H);
    castl(w_ih1, wih1_b, 3 * D_H * D_H);
    castl(w_hh1, whh1_b, 3 * D_H * D_H);
    castl(ff_w,  ffw_b,  D_OUT * D_H);

    const int ldsb = 163840;   // both layers: exactly 160KB
    hipFuncSetAttribute((const void*)&gru_scan<DIN0, true>,
                        hipFuncAttributeMaxDynamicSharedMemorySize, ldsb);
    hipFuncSetAttribute((const void*)&gru_scan<D_H, false>,
                        hipFuncAttributeMaxDynamicSharedMemorySize, ldsb);

    hipLaunchKernelGGL((gru_scan<DIN0, true>), dim3(NBLK), dim3(128), ldsb, stream,
        x_bf, wih0_b, whh0_b, b_ih0, b_hh0, h, hbuf, y0_bf, flags);
    hipLaunchKernelGGL((gru_scan<D_H, false>), dim3(NBLK), dim3(128), ldsb, stream,
        y0_bf, wih1_b, whh1_b, b_ih1, b_hh1, h + BATCH * D_H, hbuf, y1_bf,
        flags + 256);
    hipLaunchKernelGGL(ln_proj, dim3(T_SEQ * BATCH / 16), dim3(256), 0, stream,
        y1_bf, ln_g, ln_b, ffw_b, ff_b, out);
}